// Round 19
// baseline (55.059 us; speedup 1.0000x reference)
//
#include <hip/hip_runtime.h>
#include <hip/hip_bf16.h>
#include <type_traits>

typedef __attribute__((ext_vector_type(4))) float f32x4;
typedef __attribute__((ext_vector_type(8))) short bf16x8;

template <int V> using ic = std::integral_constant<int, V>;

static constexpr int B_   = 2048;
static constexpr int IN_  = 1024;
static constexpr int HID_ = 2048;
static constexpr int NB_  = 8;
static constexpr int BS_  = 256;   // block size
static constexpr int G3_  = 768;   // 3*BS_

// packed fp32x2 -> bf16x2 RNE, single VALU op (no builtin on gfx950)
__device__ __forceinline__ unsigned cvtpk(float lo, float hi) {
  unsigned r;
  asm("v_cvt_pk_bf16_f32 %0, %1, %2" : "=v"(r) : "v"(lo), "v"(hi));
  return r;
}

// ---------- fully-fused block-GRU MFMA kernel, K-step 32 ----------
// r19 = r13/r18 (52.6 us, best of 18 variants) with ONE change: the write-late
// sched_barrier(0) pin is REMOVED, allowing the compiler to interleave the
// cvt_pk + ds_write staging stream into the gate-1/gate-2 MFMA shadow
// (ds-write pipe and MFMA pipe co-issue, m114). Data deps (load->pack->write)
// and the per-step __syncthreads keep correctness identical; writes target the
// other buffer so any interleave is hazard-free.
// Tile: 128 batch rows x 64 out-cols (192 gate cols); 4 waves (2x2), wave 64x32.
// Accumulators: [0]=r (K=1280 combined), [1]=z (combined), [2]=i_n, [3]=h_n.
// LDS: 2 buffers x 20KB { A [128][32]bf16 @0, W [192][32]bf16 @8192 }.
// Staging: K32 => 5 passes (A2+W3, 40 VGPR in flight, ONE batch -> no spill).
// XCD-bijective swizzle: each XCD owns one GRU block n (W panel L2-resident).
__global__ __launch_bounds__(256, 2) void gru_mfma(
    const float* __restrict__ xf,     // [2048][1024]
    const float* __restrict__ hf,     // [2048][2048]
    const float* __restrict__ Wih,    // [8][768][1024]
    const float* __restrict__ Whh,    // [8][768][256]
    const float* __restrict__ b_ih,   // [8][768]
    const float* __restrict__ b_hh,   // [8][768]
    float* __restrict__ out)          // [2048][2048]
{
  __shared__ __align__(16) char lds[2][20480];

  const int t    = threadIdx.x;
  const int lane = t & 63;
  const int wid  = t >> 6;
  const int wm   = wid >> 1;     // wave row (0..1) -> 64-row half
  const int wn   = wid & 1;      // wave col (0..1) -> 32-col half

  // Bijective XCD swizzle: nwg=512 = 8 XCDs x 64 -> each XCD owns one GRU block n.
  const int bid = blockIdx.x;
  const int swz = (bid & 7) * 64 + (bid >> 3);
  const int mrow0 = (swz & 15) * 128;
  const int ct    = swz >> 4;
  const int n     = ct >> 2;          // GRU block index
  const int s0    = (ct & 3) * 64;    // col offset within block

  // Staging pass p targets phys offset op = p*4096 + t*16 (region-local);
  // the element that belongs there is logical ol = op ^ (((op>>6)&3)<<4)
  // (involution on byte bits [5:4] keyed by row bits [7:6]).
  int arow[2], acolE[2];
#pragma unroll
  for (int p = 0; p < 2; ++p) {
    int op = p * 4096 + t * 16;
    int ol = op ^ (((op >> 6) & 3) << 4);
    arow[p]  = ol >> 6;           // 0..127
    acolE[p] = (ol & 63) >> 1;    // element offset {0,8,16,24}
  }
  int wgrow[3], wcolE[3];
#pragma unroll
  for (int q = 0; q < 3; ++q) {
    int op = q * 4096 + t * 16;
    int ol = op ^ (((op >> 6) & 3) << 4);
    int wr = ol >> 6;             // 0..191
    wgrow[q]  = n * G3_ + (wr >> 6) * BS_ + s0 + (wr & 63);  // global W row
    wcolE[q]  = (ol & 63) >> 1;
  }

  f32x4 acc[4][4][2] = {};   // [set][mi][ni]
  float4 sa[2][2];           // A staging (16 VGPR)
  float4 sw[3][2];           // W staging (24 VGPR)

  auto issue = [&](int tt) {             // 10 coalesced fp32 loads (40 VGPR)
#pragma unroll
    for (int p = 0; p < 2; ++p) {
      const float* src = (tt < 32)
        ? xf + (size_t)(mrow0 + arow[p]) * IN_  + tt * 32 + acolE[p]
        : hf + (size_t)(mrow0 + arow[p]) * HID_ + n * BS_ + (tt - 32) * 32 + acolE[p];
      sa[p][0] = *reinterpret_cast<const float4*>(src);
      sa[p][1] = *reinterpret_cast<const float4*>(src + 4);
    }
#pragma unroll
    for (int q = 0; q < 3; ++q) {
      const float* src = (tt < 32)
        ? Wih + (size_t)wgrow[q] * IN_ + tt * 32 + wcolE[q]
        : Whh + (size_t)wgrow[q] * BS_ + (tt - 32) * 32 + wcolE[q];
      sw[q][0] = *reinterpret_cast<const float4*>(src);
      sw[q][1] = *reinterpret_cast<const float4*>(src + 4);
    }
  };
  auto pack8 = [&](const float4& a, const float4& b) {
    union { unsigned u[4]; bf16x8 v; } r;
    r.u[0] = cvtpk(a.x, a.y); r.u[1] = cvtpk(a.z, a.w);
    r.u[2] = cvtpk(b.x, b.y); r.u[3] = cvtpk(b.z, b.w);
    return r.v;
  };
  auto writeAll = [&](int buf) {         // cvt + 5 ds_write_b128 (linear phys)
    char* base = (char*)lds[buf];
#pragma unroll
    for (int p = 0; p < 2; ++p)
      *reinterpret_cast<bf16x8*>(base + p * 4096 + t * 16) = pack8(sa[p][0], sa[p][1]);
#pragma unroll
    for (int q = 0; q < 3; ++q)
      *reinterpret_cast<bf16x8*>(base + 8192 + q * 4096 + t * 16) = pack8(sw[q][0], sw[q][1]);
  };

  auto compute = [&](int buf, auto ph1c) {
    constexpr bool PH1 = decltype(ph1c)::value;
    const char* base = (const char*)lds[buf];
    bf16x8 af[4];
#pragma unroll
    for (int mi = 0; mi < 4; ++mi) {
      int ar  = wm * 64 + mi * 16 + (lane & 15);
      int off = (ar * 64 + ((lane >> 4) * 16)) ^ ((ar & 3) << 4);
      af[mi] = *reinterpret_cast<const bf16x8*>(base + off);
    }
    __builtin_amdgcn_s_setprio(1);
#pragma unroll
    for (int g = 0; g < 3; ++g) {
      bf16x8 wf[2];
#pragma unroll
      for (int ni = 0; ni < 2; ++ni) {
        int wr  = g * 64 + wn * 32 + ni * 16 + (lane & 15);
        int off = (wr * 64 + ((lane >> 4) * 16)) ^ ((wr & 3) << 4);
        wf[ni] = *reinterpret_cast<const bf16x8*>(base + 8192 + off);
      }
      constexpr int set2 = PH1 ? 2 : 3;
      const int set = (g < 2) ? g : set2;
#pragma unroll
      for (int mi = 0; mi < 4; ++mi)
#pragma unroll
        for (int ni = 0; ni < 2; ++ni)
          acc[set][mi][ni] = __builtin_amdgcn_mfma_f32_16x16x32_bf16(
              af[mi], wf[ni], acc[set][mi][ni], 0, 0, 0);
    }
    __builtin_amdgcn_s_setprio(0);
  };

  // ---- prologue: stage tile 0 into buf0 ----
  issue(0);
  writeAll(0);
  __syncthreads();

  // ---- 40 K-steps (32 input + 8 hidden), fully unrolled, ONE barrier each ----
#pragma unroll
  for (int tt = 0; tt < 40; ++tt) {
    const int cur = tt & 1;

    if (tt < 39) issue(tt + 1);             // T14: issue early
    __builtin_amdgcn_sched_barrier(0);      // loads stay above compute
    if (tt < 32) compute(cur, std::true_type{});
    else         compute(cur, std::false_type{});
    // (r19: write-late pin removed - pack/write may interleave into the
    //  gate-1/2 MFMA shadow; barrier below still orders everything)
    if (tt < 39) writeAll(cur ^ 1);
    __syncthreads();   // writes visible; reads of cur retired; loads consumed
  }

  // ---- epilogue: gates + output ----
#pragma unroll
  for (int ni = 0; ni < 2; ++ni) {
    int scol = s0 + wn * 32 + ni * 16 + (lane & 15);
    float br_i = b_ih[n * G3_ + 0 * BS_ + scol];
    float bz_i = b_ih[n * G3_ + 1 * BS_ + scol];
    float bn_i = b_ih[n * G3_ + 2 * BS_ + scol];
    float br_h = b_hh[n * G3_ + 0 * BS_ + scol];
    float bz_h = b_hh[n * G3_ + 1 * BS_ + scol];
    float bn_h = b_hh[n * G3_ + 2 * BS_ + scol];
    int gcol = n * BS_ + scol;
#pragma unroll
    for (int mi = 0; mi < 4; ++mi) {
#pragma unroll
      for (int i = 0; i < 4; ++i) {
        int row = mrow0 + wm * 64 + mi * 16 + (lane >> 4) * 4 + i;  // C/D: col=lane&15, row=(lane>>4)*4+reg
        float hprev = hf[(size_t)row * HID_ + gcol];
        float rr = acc[0][mi][ni][i] + br_i + br_h;
        float zz = acc[1][mi][ni][i] + bz_i + bz_h;
        float r  = 1.f / (1.f + __expf(-rr));
        float z  = 1.f / (1.f + __expf(-zz));
        float ng = tanhf(acc[2][mi][ni][i] + bn_i + r * (acc[3][mi][ni][i] + bn_h));
        out[(size_t)row * HID_ + gcol] = (1.f - z) * ng + z * hprev;
      }
    }
  }
}

extern "C" void kernel_launch(void* const* d_in, const int* in_sizes, int n_in,
                              void* d_out, int out_size, void* d_ws, size_t ws_size,
                              hipStream_t stream) {
  const float* x   = (const float*)d_in[0];
  const float* h   = (const float*)d_in[1];
  const float* Wih = (const float*)d_in[2];
  const float* Whh = (const float*)d_in[3];
  const float* bih = (const float*)d_in[4];
  const float* bhh = (const float*)d_in[5];
  float* out = (float*)d_out;
  (void)d_ws; (void)ws_size;

  gru_mfma<<<512, 256, 0, stream>>>(x, h, Wih, Whh, bih, bhh, out);
}

// Round 20
// 52.541 us; speedup vs baseline: 1.0479x; 1.0479x over previous
//
#include <hip/hip_runtime.h>
#include <hip/hip_bf16.h>
#include <type_traits>

typedef __attribute__((ext_vector_type(4))) float f32x4;
typedef __attribute__((ext_vector_type(8))) short bf16x8;

template <int V> using ic = std::integral_constant<int, V>;

static constexpr int B_   = 2048;
static constexpr int IN_  = 1024;
static constexpr int HID_ = 2048;
static constexpr int NB_  = 8;
static constexpr int BS_  = 256;   // block size
static constexpr int G3_  = 768;   // 3*BS_

// packed fp32x2 -> bf16x2 RNE, single VALU op (no builtin on gfx950)
__device__ __forceinline__ unsigned cvtpk(float lo, float hi) {
  unsigned r;
  asm("v_cvt_pk_bf16_f32 %0, %1, %2" : "=v"(r) : "v"(lo), "v"(hi));
  return r;
}

// ---------- fully-fused block-GRU MFMA kernel, K-step 32 (FINAL: 52.6 us) ----------
// Best of 19 measured variants (r13 config, reproduced r18; r19's pin removal
// regressed -2.5us -> write-late sched_barrier(0) pin RESTORED).
// Single launch, no workspace: fp32->bf16 conversion rides inside staging.
// Tile: 128 batch rows x 64 out-cols (192 gate cols); 4 waves (2x2), wave 64x32.
// Accumulators: [0]=r (K=1280 combined), [1]=z (combined), [2]=i_n, [3]=h_n.
// LDS: 2 buffers x 20KB { A [128][32]bf16 @0, W [192][32]bf16 @8192 }.
// Staging: K32 => 5 passes (A2+W3, 40 VGPR in flight, ONE batch -> no spill):
// issue 10 fp32 loads at step top -> compute (24 MFMAs) hides latency ->
// cvt_pk + 5 ds_write_b128 at tail -> __syncthreads.
// XCD-bijective swizzle: each XCD owns one GRU block n (W panel L2-resident).
__global__ __launch_bounds__(256, 2) void gru_mfma(
    const float* __restrict__ xf,     // [2048][1024]
    const float* __restrict__ hf,     // [2048][2048]
    const float* __restrict__ Wih,    // [8][768][1024]
    const float* __restrict__ Whh,    // [8][768][256]
    const float* __restrict__ b_ih,   // [8][768]
    const float* __restrict__ b_hh,   // [8][768]
    float* __restrict__ out)          // [2048][2048]
{
  __shared__ __align__(16) char lds[2][20480];

  const int t    = threadIdx.x;
  const int lane = t & 63;
  const int wid  = t >> 6;
  const int wm   = wid >> 1;     // wave row (0..1) -> 64-row half
  const int wn   = wid & 1;      // wave col (0..1) -> 32-col half

  // Bijective XCD swizzle: nwg=512 = 8 XCDs x 64 -> each XCD owns one GRU block n.
  const int bid = blockIdx.x;
  const int swz = (bid & 7) * 64 + (bid >> 3);
  const int mrow0 = (swz & 15) * 128;
  const int ct    = swz >> 4;
  const int n     = ct >> 2;          // GRU block index
  const int s0    = (ct & 3) * 64;    // col offset within block

  // Staging pass p targets phys offset op = p*4096 + t*16 (region-local);
  // the element that belongs there is logical ol = op ^ (((op>>6)&3)<<4)
  // (involution on byte bits [5:4] keyed by row bits [7:6]).
  int arow[2], acolE[2];
#pragma unroll
  for (int p = 0; p < 2; ++p) {
    int op = p * 4096 + t * 16;
    int ol = op ^ (((op >> 6) & 3) << 4);
    arow[p]  = ol >> 6;           // 0..127
    acolE[p] = (ol & 63) >> 1;    // element offset {0,8,16,24}
  }
  int wgrow[3], wcolE[3];
#pragma unroll
  for (int q = 0; q < 3; ++q) {
    int op = q * 4096 + t * 16;
    int ol = op ^ (((op >> 6) & 3) << 4);
    int wr = ol >> 6;             // 0..191
    wgrow[q]  = n * G3_ + (wr >> 6) * BS_ + s0 + (wr & 63);  // global W row
    wcolE[q]  = (ol & 63) >> 1;
  }

  f32x4 acc[4][4][2] = {};   // [set][mi][ni]
  float4 sa[2][2];           // A staging (16 VGPR)
  float4 sw[3][2];           // W staging (24 VGPR)

  auto issue = [&](int tt) {             // 10 coalesced fp32 loads (40 VGPR)
#pragma unroll
    for (int p = 0; p < 2; ++p) {
      const float* src = (tt < 32)
        ? xf + (size_t)(mrow0 + arow[p]) * IN_  + tt * 32 + acolE[p]
        : hf + (size_t)(mrow0 + arow[p]) * HID_ + n * BS_ + (tt - 32) * 32 + acolE[p];
      sa[p][0] = *reinterpret_cast<const float4*>(src);
      sa[p][1] = *reinterpret_cast<const float4*>(src + 4);
    }
#pragma unroll
    for (int q = 0; q < 3; ++q) {
      const float* src = (tt < 32)
        ? Wih + (size_t)wgrow[q] * IN_ + tt * 32 + wcolE[q]
        : Whh + (size_t)wgrow[q] * BS_ + (tt - 32) * 32 + wcolE[q];
      sw[q][0] = *reinterpret_cast<const float4*>(src);
      sw[q][1] = *reinterpret_cast<const float4*>(src + 4);
    }
  };
  auto pack8 = [&](const float4& a, const float4& b) {
    union { unsigned u[4]; bf16x8 v; } r;
    r.u[0] = cvtpk(a.x, a.y); r.u[1] = cvtpk(a.z, a.w);
    r.u[2] = cvtpk(b.x, b.y); r.u[3] = cvtpk(b.z, b.w);
    return r.v;
  };
  auto writeAll = [&](int buf) {         // cvt + 5 ds_write_b128 (linear phys)
    char* base = (char*)lds[buf];
#pragma unroll
    for (int p = 0; p < 2; ++p)
      *reinterpret_cast<bf16x8*>(base + p * 4096 + t * 16) = pack8(sa[p][0], sa[p][1]);
#pragma unroll
    for (int q = 0; q < 3; ++q)
      *reinterpret_cast<bf16x8*>(base + 8192 + q * 4096 + t * 16) = pack8(sw[q][0], sw[q][1]);
  };

  auto compute = [&](int buf, auto ph1c) {
    constexpr bool PH1 = decltype(ph1c)::value;
    const char* base = (const char*)lds[buf];
    bf16x8 af[4];
#pragma unroll
    for (int mi = 0; mi < 4; ++mi) {
      int ar  = wm * 64 + mi * 16 + (lane & 15);
      int off = (ar * 64 + ((lane >> 4) * 16)) ^ ((ar & 3) << 4);
      af[mi] = *reinterpret_cast<const bf16x8*>(base + off);
    }
    __builtin_amdgcn_s_setprio(1);
#pragma unroll
    for (int g = 0; g < 3; ++g) {
      bf16x8 wf[2];
#pragma unroll
      for (int ni = 0; ni < 2; ++ni) {
        int wr  = g * 64 + wn * 32 + ni * 16 + (lane & 15);
        int off = (wr * 64 + ((lane >> 4) * 16)) ^ ((wr & 3) << 4);
        wf[ni] = *reinterpret_cast<const bf16x8*>(base + 8192 + off);
      }
      constexpr int set2 = PH1 ? 2 : 3;
      const int set = (g < 2) ? g : set2;
#pragma unroll
      for (int mi = 0; mi < 4; ++mi)
#pragma unroll
        for (int ni = 0; ni < 2; ++ni)
          acc[set][mi][ni] = __builtin_amdgcn_mfma_f32_16x16x32_bf16(
              af[mi], wf[ni], acc[set][mi][ni], 0, 0, 0);
    }
    __builtin_amdgcn_s_setprio(0);
  };

  // ---- prologue: stage tile 0 into buf0 ----
  issue(0);
  writeAll(0);
  __syncthreads();

  // ---- 40 K-steps (32 input + 8 hidden), fully unrolled, ONE barrier each ----
#pragma unroll
  for (int tt = 0; tt < 40; ++tt) {
    const int cur = tt & 1;

    if (tt < 39) issue(tt + 1);             // T14: issue early
    __builtin_amdgcn_sched_barrier(0);      // loads stay above compute
    if (tt < 32) compute(cur, std::true_type{});
    else         compute(cur, std::false_type{});
    __builtin_amdgcn_sched_barrier(0);      // write-late boundary (protective: r19)
    if (tt < 39) writeAll(cur ^ 1);
    __syncthreads();   // writes visible; reads of cur retired; loads consumed
  }

  // ---- epilogue: gates + output ----
#pragma unroll
  for (int ni = 0; ni < 2; ++ni) {
    int scol = s0 + wn * 32 + ni * 16 + (lane & 15);
    float br_i = b_ih[n * G3_ + 0 * BS_ + scol];
    float bz_i = b_ih[n * G3_ + 1 * BS_ + scol];
    float bn_i = b_ih[n * G3_ + 2 * BS_ + scol];
    float br_h = b_hh[n * G3_ + 0 * BS_ + scol];
    float bz_h = b_hh[n * G3_ + 1 * BS_ + scol];
    float bn_h = b_hh[n * G3_ + 2 * BS_ + scol];
    int gcol = n * BS_ + scol;
#pragma unroll
    for (int mi = 0; mi < 4; ++mi) {
#pragma unroll
      for (int i = 0; i < 4; ++i) {
        int row = mrow0 + wm * 64 + mi * 16 + (lane >> 4) * 4 + i;  // C/D: col=lane&15, row=(lane>>4)*4+reg
        float hprev = hf[(size_t)row * HID_ + gcol];
        float rr = acc[0][mi][ni][i] + br_i + br_h;
        float zz = acc[1][mi][ni][i] + bz_i + bz_h;
        float r  = 1.f / (1.f + __expf(-rr));
        float z  = 1.f / (1.f + __expf(-zz));
        float ng = tanhf(acc[2][mi][ni][i] + bn_i + r * (acc[3][mi][ni][i] + bn_h));
        out[(size_t)row * HID_ + gcol] = (1.f - z) * ng + z * hprev;
      }
    }
  }
}

extern "C" void kernel_launch(void* const* d_in, const int* in_sizes, int n_in,
                              void* d_out, int out_size, void* d_ws, size_t ws_size,
                              hipStream_t stream) {
  const float* x   = (const float*)d_in[0];
  const float* h   = (const float*)d_in[1];
  const float* Wih = (const float*)d_in[2];
  const float* Whh = (const float*)d_in[3];
  const float* bih = (const float*)d_in[4];
  const float* bhh = (const float*)d_in[5];
  float* out = (float*)d_out;
  (void)d_ws; (void)ws_size;

  gru_mfma<<<512, 256, 0, stream>>>(x, h, Wih, Whh, bih, bhh, out);
}